// Round 6
// baseline (316.119 us; speedup 1.0000x reference)
//
#include <hip/hip_runtime.h>
#include <hip/hip_fp16.h>

#define FD 128

typedef __attribute__((ext_vector_type(8))) short bf16x8;
typedef __attribute__((ext_vector_type(4))) float f32x4;

__device__ __forceinline__ float lrelu(float x, float s){ return x > 0.f ? x : s*x; }

__device__ __forceinline__ unsigned short f2bf(float f){
  unsigned u = __builtin_bit_cast(unsigned, f);
  return (unsigned short)((u + 0x7FFFu + ((u >> 16) & 1u)) >> 16);
}
__device__ __forceinline__ float bf2f(unsigned short h){
  unsigned u = ((unsigned)h) << 16;
  return __builtin_bit_cast(float, u);
}

// ---------------- count (XCD-partitioned) + wprep fused ----------------
// Blocks [0,NBC): count by dst, XCD-local atomics. Blocks [NBC, NBC+144): W prep.
// WT row-major [144][128] bf16 hi/lo; output channel c -> row w(c)=(c&7)*16+(c>>3).
__global__ __launch_bounds__(256) void count_wprep_kernel(const int* __restrict__ dst,
    int* __restrict__ counts, int E, unsigned rscale, int nchunk, int nbc,
    const float* __restrict__ W1, const float* __restrict__ W2,
    const float* __restrict__ aS1, const float* __restrict__ aD1,
    const float* __restrict__ aS2, const float* __restrict__ aD2,
    unsigned short* __restrict__ WT1h, unsigned short* __restrict__ WT1l,
    unsigned short* __restrict__ WT2h, unsigned short* __restrict__ WT2l)
{
  int b = blockIdx.x;
  if (b < nbc){
    int xcd = b & 7, chunk = b >> 3;
    int nv = E >> 2;
    for (int v = chunk*256 + threadIdx.x; v < nv; v += nchunk*256){
      int4 d4 = ((const int4*)dst)[v];
      #pragma unroll
      for (int t = 0; t < 4; ++t){
        int d = (&d4.x)[t];
        unsigned r = (unsigned)(((unsigned long long)(unsigned)d * rscale) >> 32);
        if ((int)r == xcd) atomicAdd(&counts[d], 1);
      }
    }
    if (chunk == 0 && threadIdx.x < (E & 3)){
      int i = (E & ~3) + threadIdx.x;
      int d = dst[i];
      unsigned r = (unsigned)(((unsigned long long)(unsigned)d * rscale) >> 32);
      if ((int)r == xcd) atomicAdd(&counts[d], 1);
    }
    return;
  }
  int id = (b - nbc)*256 + threadIdx.x;
  if (id < 32768){
    const float* W = (id < 16384) ? W1 : W2;
    unsigned short* Th = (id < 16384) ? WT1h : WT2h;
    unsigned short* Tl = (id < 16384) ? WT1l : WT2l;
    int idx = id & 16383;
    int k = idx >> 7, c = idx & 127;
    int w = ((c & 7) << 4) | (c >> 3);
    float v = W[idx];
    unsigned short h = f2bf(v);
    Th[w*FD + k] = h;
    Tl[w*FD + k] = f2bf(v - bf2f(h));
  } else if (id < 34816){
    int id2 = id - 32768;
    int layer = id2 >> 10;
    int id3 = id2 & 1023;
    int k = id3 >> 3, cc = id3 & 7;
    const float* W  = layer ? W2 : W1;
    const float* av = (cc < 4) ? (layer ? aS2 : aS1) : (layer ? aD2 : aD1);
    unsigned short* Th = layer ? WT2h : WT1h;
    unsigned short* Tl = layer ? WT2l : WT1l;
    int h = cc & 3, base = h*32;
    float acc = 0.f;
    #pragma unroll 8
    for (int c = 0; c < 32; ++c) acc += W[k*FD + base + c] * av[base + c];
    unsigned short hh = f2bf(acc);
    Th[(128 + cc)*FD + k] = hh;
    Tl[(128 + cc)*FD + k] = f2bf(acc - bf2f(hh));
  } else if (id < 36864){
    int id2 = id - 34816;
    int layer = id2 >> 10;
    int id3 = id2 & 1023;
    int row = 136 + (id3 >> 7), k = id3 & 127;
    unsigned short* Th = layer ? WT2h : WT1h;
    unsigned short* Tl = layer ? WT2l : WT1l;
    Th[row*FD + k] = 0;
    Tl[row*FD + k] = 0;
  }
}

// ---------------- scan of (counts[i]+1) + self-loop insertion ----------------
// +1 reserves the self-loop slot (last slot of each row); since the scan knows
// offsets[d+1] it writes csr[offsets[d+1]-1] = d directly (fill never touches it).
__global__ __launch_bounds__(1024) void scan_kernel(const int* __restrict__ counts,
                                                    int* __restrict__ offsets,
                                                    int* __restrict__ csr, int n){
  __shared__ int wsum[16];
  __shared__ int carry_s;
  int tid = threadIdx.x, lane = tid & 63, wv = tid >> 6;
  if (tid == 0) carry_s = 0;
  __syncthreads();
  for (int base = 0; base < n; base += 4096){
    int idx = base + tid*4;
    int v0=0,v1=0,v2=0,v3=0;
    if (idx + 3 < n){
      int4 t = *(const int4*)(counts + idx);
      v0=t.x+1; v1=t.y+1; v2=t.z+1; v3=t.w+1;
    } else {
      if (idx   < n) v0 = counts[idx]+1;
      if (idx+1 < n) v1 = counts[idx+1]+1;
      if (idx+2 < n) v2 = counts[idx+2]+1;
      if (idx+3 < n) v3 = counts[idx+3]+1;
    }
    int p0=v0, p1=p0+v1, p2=p1+v2, p3=p2+v3;
    int incl = p3;
    #pragma unroll
    for (int off = 1; off < 64; off <<= 1){
      int t = __shfl_up(incl, off);
      if (lane >= off) incl += t;
    }
    if (lane == 63) wsum[wv] = incl;
    __syncthreads();
    if (wv == 0 && lane < 16){
      int s = wsum[lane];
      #pragma unroll
      for (int off = 1; off < 16; off <<= 1){
        int t = __shfl_up(s, off);
        if (lane >= off) s += t;
      }
      wsum[lane] = s;
    }
    __syncthreads();
    int woff = (wv > 0) ? wsum[wv-1] : 0;
    int carry = carry_s;
    int off0 = carry + woff + incl - p3;
    if (idx   < n){ offsets[idx]   = off0;      csr[off0 + p0 - 1] = idx;   }
    if (idx+1 < n){ offsets[idx+1] = off0 + p0; csr[off0 + p1 - 1] = idx+1; }
    if (idx+2 < n){ offsets[idx+2] = off0 + p1; csr[off0 + p2 - 1] = idx+2; }
    if (idx+3 < n){ offsets[idx+3] = off0 + p2; csr[off0 + p3 - 1] = idx+3; }
    __syncthreads();
    if (tid == 0) carry_s = carry + wsum[15];
    __syncthreads();
  }
  if (tid == 0) offsets[n] = carry_s;
}

// ---------------- fill (XCD-partitioned; slots 0..deg-1) ----------------
__global__ __launch_bounds__(256) void fill_part_kernel(const int* __restrict__ ei,
    const int* __restrict__ offsets, int* __restrict__ counts, int* __restrict__ csr,
    int E, unsigned rscale, int nchunk){
  int b = blockIdx.x;
  int xcd = b & 7, chunk = b >> 3;
  int nv = E >> 2;
  for (int v = chunk*256 + threadIdx.x; v < nv; v += nchunk*256){
    int4 s4 = ((const int4*)ei)[v];
    int4 d4 = ((const int4*)(ei + E))[v];
    #pragma unroll
    for (int t = 0; t < 4; ++t){
      int d = (&d4.x)[t];
      unsigned r = (unsigned)(((unsigned long long)(unsigned)d * rscale) >> 32);
      if ((int)r == xcd){
        int c = atomicSub(&counts[d], 1) - 1;
        csr[offsets[d] + c] = (&s4.x)[t];
      }
    }
  }
  if (chunk == 0 && threadIdx.x < (E & 3)){
    int i = (E & ~3) + threadIdx.x;
    int d = ei[E + i];
    unsigned r = (unsigned)(((unsigned long long)(unsigned)d * rscale) >> 32);
    if ((int)r == xcd){
      int c = atomicSub(&counts[d], 1) - 1;
      csr[offsets[d] + c] = ei[i];
    }
  }
}

// ---------------- MFMA GEMM: [H(fp16, packed) | attS | attD] ----------------
template<int SPLITIN>
__global__ __launch_bounds__(256) void gemm_mfma_kernel(
    const float* __restrict__ Xf,
    const unsigned short* __restrict__ Xh, const unsigned short* __restrict__ Xl,
    const unsigned short* __restrict__ WTh, const unsigned short* __restrict__ WTl,
    uint4* __restrict__ H16, float* __restrict__ attS, float* __restrict__ attD, int n)
{
  int tid = threadIdx.x;
  int wv = tid >> 6, lane = tid & 63;
  int g = lane >> 4, r = lane & 15;
  int rbase = blockIdx.x*64 + wv*16;
  int arow = rbase + r; if (arow >= n) arow = n - 1;

  bf16x8 Ah[4], Al[4];
  if (SPLITIN){
    const bf16x8* ph = (const bf16x8*)(Xh + (size_t)arow*FD);
    const bf16x8* pl = (const bf16x8*)(Xl + (size_t)arow*FD);
    #pragma unroll
    for (int kc = 0; kc < 4; ++kc){ Ah[kc] = ph[kc*4 + g]; Al[kc] = pl[kc*4 + g]; }
  } else {
    const float4* px = (const float4*)(Xf + (size_t)arow*FD);
    #pragma unroll
    for (int kc = 0; kc < 4; ++kc){
      float4 x0 = px[(kc*4 + g)*2];
      float4 x1 = px[(kc*4 + g)*2 + 1];
      float xs[8] = {x0.x,x0.y,x0.z,x0.w,x1.x,x1.y,x1.z,x1.w};
      #pragma unroll
      for (int t = 0; t < 8; ++t){
        unsigned short hh = f2bf(xs[t]);
        Ah[kc][t] = (short)hh;
        Al[kc][t] = (short)f2bf(xs[t] - bf2f(hh));
      }
    }
  }

  f32x4 acc[9];
  #pragma unroll
  for (int ct = 0; ct < 9; ++ct) acc[ct] = (f32x4){0.f,0.f,0.f,0.f};

  #pragma unroll
  for (int ct = 0; ct < 9; ++ct){
    int wrow = ct*16 + r;
    const bf16x8* bh = (const bf16x8*)(WTh + wrow*FD);
    const bf16x8* bl = (const bf16x8*)(WTl + wrow*FD);
    #pragma unroll
    for (int kc = 0; kc < 4; ++kc){
      bf16x8 Bh = bh[kc*4 + g];
      bf16x8 Bl = bl[kc*4 + g];
      acc[ct] = __builtin_amdgcn_mfma_f32_16x16x32_bf16(Ah[kc], Bh, acc[ct], 0, 0, 0);
      acc[ct] = __builtin_amdgcn_mfma_f32_16x16x32_bf16(Ah[kc], Bl, acc[ct], 0, 0, 0);
      acc[ct] = __builtin_amdgcn_mfma_f32_16x16x32_bf16(Al[kc], Bh, acc[ct], 0, 0, 0);
    }
  }

  #pragma unroll
  for (int j = 0; j < 4; ++j){
    int row = rbase + g*4 + j;
    if (row < n){
      __half2 p0 = __float22half2_rn(make_float2(acc[0][j], acc[1][j]));
      __half2 p1 = __float22half2_rn(make_float2(acc[2][j], acc[3][j]));
      __half2 p2 = __float22half2_rn(make_float2(acc[4][j], acc[5][j]));
      __half2 p3 = __float22half2_rn(make_float2(acc[6][j], acc[7][j]));
      uint4 pk;
      pk.x = __builtin_bit_cast(unsigned, p0);
      pk.y = __builtin_bit_cast(unsigned, p1);
      pk.z = __builtin_bit_cast(unsigned, p2);
      pk.w = __builtin_bit_cast(unsigned, p3);
      H16[(size_t)row*16 + r] = pk;
      if (r < 4)      attS[row*4 + r]       = acc[8][j];
      else if (r < 8) attD[row*4 + (r - 4)] = acc[8][j];
    }
  }
}

// ---------------- per-dst softmax + aggregate (one wave per dst) ----------------
// Gather: 8 edges/iter, 8 lanes/edge (grp=lane>>3, pos=lane&7), 2x dwordx4 per lane.
// Lane accumulates 16 channels: acc[0..7]=ch 8pos..+7 (head pos>>2),
// acc[8..15]=ch 64+8pos..+7 (head 2+(pos>>2)). Stash [sb,_,p0,p2,p1,p3] stride 6 so
// one aligned ds_read_b64 at slot 2+2*hsel yields (pA,pB). Cross-group reduce:
// shfl_xor 8/16/32; epilogue on lanes 0-7 (pos=lane), dwordx4 packed stores.
template<int OUT>
__global__ __launch_bounds__(256) void agg_kernel(
    const uint4* __restrict__ H16, const float* __restrict__ attS, const float* __restrict__ attD,
    const int* __restrict__ csr, const int* __restrict__ offsets,
    const float* __restrict__ bias, const float* __restrict__ wfc, const float* __restrict__ bfc,
    uint4* __restrict__ oh, uint4* __restrict__ ol,
    float* __restrict__ out, int n)
{
  __shared__ float lds[4][64*6];
  int wid = (int)((blockIdx.x * (size_t)blockDim.x + threadIdx.x) >> 6);
  int lane = threadIdx.x & 63;
  if (wid >= n) return;
  int grp = lane >> 3, pos = lane & 7;
  int hsel = pos >> 2;
  float* wl = lds[threadIdx.x >> 6];
  int* wli = (int*)wl;

  int start = offsets[wid], end = offsets[wid+1];
  float4 ad4 = ((const float4*)attD)[wid];

  float z0=0.f, z1=0.f, z2=0.f, z3=0.f;
  float acc[16];
  #pragma unroll
  for (int k = 0; k < 16; ++k) acc[k] = 0.f;

  for (int base2 = start; base2 < end; base2 += 64){
    int cnt = end - base2; if (cnt > 64) cnt = 64;
    float p0,p1,p2,p3; int sb = 0;
    if (lane < cnt){
      int s = csr[base2 + lane];
      sb = s << 4;                    // 16 uint4 per 256B fp16 row
      float4 as4 = ((const float4*)attS)[s];
      p0 = __expf(lrelu(as4.x + ad4.x, 0.2f));
      p1 = __expf(lrelu(as4.y + ad4.y, 0.2f));
      p2 = __expf(lrelu(as4.z + ad4.z, 0.2f));
      p3 = __expf(lrelu(as4.w + ad4.w, 0.2f));
    } else { p0=p1=p2=p3=0.f; }
    z0+=p0; z1+=p1; z2+=p2; z3+=p3;
    wli[lane*6]  = sb;
    wl[lane*6+2] = p0; wl[lane*6+3] = p2;   // (pA,pB) for hsel=0
    wl[lane*6+4] = p1; wl[lane*6+5] = p3;   // (pA,pB) for hsel=1
    asm volatile("s_waitcnt lgkmcnt(0)" ::: "memory");
    __builtin_amdgcn_sched_barrier(0);
    #pragma unroll 2
    for (int jj = grp; jj < cnt; jj += 8){
      int sbj = wli[jj*6];
      float2 pj = *(const float2*)&wl[jj*6 + 2 + (hsel<<1)];
      uint4 u0 = H16[(unsigned)(sbj + pos)];
      uint4 u1 = H16[(unsigned)(sbj + 8 + pos)];
      float2 t;
      t = __half22float2(__builtin_bit_cast(__half2, u0.x)); acc[0] += pj.x*t.x; acc[1] += pj.x*t.y;
      t = __half22float2(__builtin_bit_cast(__half2, u0.y)); acc[2] += pj.x*t.x; acc[3] += pj.x*t.y;
      t = __half22float2(__builtin_bit_cast(__half2, u0.z)); acc[4] += pj.x*t.x; acc[5] += pj.x*t.y;
      t = __half22float2(__builtin_bit_cast(__half2, u0.w)); acc[6] += pj.x*t.x; acc[7] += pj.x*t.y;
      t = __half22float2(__builtin_bit_cast(__half2, u1.x)); acc[8] += pj.y*t.x; acc[9] += pj.y*t.y;
      t = __half22float2(__builtin_bit_cast(__half2, u1.y)); acc[10]+= pj.y*t.x; acc[11]+= pj.y*t.y;
      t = __half22float2(__builtin_bit_cast(__half2, u1.z)); acc[12]+= pj.y*t.x; acc[13]+= pj.y*t.y;
      t = __half22float2(__builtin_bit_cast(__half2, u1.w)); acc[14]+= pj.y*t.x; acc[15]+= pj.y*t.y;
    }
    __builtin_amdgcn_sched_barrier(0);
  }

  #pragma unroll
  for (int off = 32; off >= 1; off >>= 1){
    z0+=__shfl_xor(z0,off); z1+=__shfl_xor(z1,off);
    z2+=__shfl_xor(z2,off); z3+=__shfl_xor(z3,off);
  }
  #pragma unroll
  for (int k = 0; k < 16; ++k){
    acc[k] += __shfl_xor(acc[k], 8);
    acc[k] += __shfl_xor(acc[k], 16);
    acc[k] += __shfl_xor(acc[k], 32);
  }

  if (lane < 8){
    float invl = 1.f / (((lane < 4) ? z0 : z1) + 1e-16f);
    float invh = 1.f / (((lane < 4) ? z2 : z3) + 1e-16f);
    const float4* b4 = (const float4*)bias;
    float4 b0 = b4[2*lane], b1 = b4[2*lane+1], b2 = b4[16+2*lane], b3 = b4[16+2*lane+1];
    float o[16];
    o[0]=lrelu(acc[0]*invl+b0.x,0.01f); o[1]=lrelu(acc[1]*invl+b0.y,0.01f);
    o[2]=lrelu(acc[2]*invl+b0.z,0.01f); o[3]=lrelu(acc[3]*invl+b0.w,0.01f);
    o[4]=lrelu(acc[4]*invl+b1.x,0.01f); o[5]=lrelu(acc[5]*invl+b1.y,0.01f);
    o[6]=lrelu(acc[6]*invl+b1.z,0.01f); o[7]=lrelu(acc[7]*invl+b1.w,0.01f);
    o[8]=lrelu(acc[8]*invh+b2.x,0.01f); o[9]=lrelu(acc[9]*invh+b2.y,0.01f);
    o[10]=lrelu(acc[10]*invh+b2.z,0.01f); o[11]=lrelu(acc[11]*invh+b2.w,0.01f);
    o[12]=lrelu(acc[12]*invh+b3.x,0.01f); o[13]=lrelu(acc[13]*invh+b3.y,0.01f);
    o[14]=lrelu(acc[14]*invh+b3.z,0.01f); o[15]=lrelu(acc[15]*invh+b3.w,0.01f);
    if (OUT){
      const float4* w4 = (const float4*)wfc;
      float4 w0 = w4[2*lane], w1 = w4[2*lane+1], w2 = w4[16+2*lane], w3 = w4[16+2*lane+1];
      float t = o[0]*w0.x + o[1]*w0.y + o[2]*w0.z + o[3]*w0.w
              + o[4]*w1.x + o[5]*w1.y + o[6]*w1.z + o[7]*w1.w
              + o[8]*w2.x + o[9]*w2.y + o[10]*w2.z + o[11]*w2.w
              + o[12]*w3.x + o[13]*w3.y + o[14]*w3.z + o[15]*w3.w;
      t += __shfl_xor(t, 1); t += __shfl_xor(t, 2); t += __shfl_xor(t, 4);
      if (lane == 0) out[wid] = t + bfc[0];
    } else {
      unsigned hh[16], ll[16];
      #pragma unroll
      for (int i = 0; i < 16; ++i){
        unsigned short h = f2bf(o[i]);
        hh[i] = h; ll[i] = f2bf(o[i] - bf2f(h));
      }
      uint4 ph0 = {hh[0]|(hh[1]<<16), hh[2]|(hh[3]<<16), hh[4]|(hh[5]<<16), hh[6]|(hh[7]<<16)};
      uint4 pl0 = {ll[0]|(ll[1]<<16), ll[2]|(ll[3]<<16), ll[4]|(ll[5]<<16), ll[6]|(ll[7]<<16)};
      uint4 ph1 = {hh[8]|(hh[9]<<16), hh[10]|(hh[11]<<16), hh[12]|(hh[13]<<16), hh[14]|(hh[15]<<16)};
      uint4 pl1 = {ll[8]|(ll[9]<<16), ll[10]|(ll[11]<<16), ll[12]|(ll[13]<<16), ll[14]|(ll[15]<<16)};
      oh[(size_t)wid*16 + lane]     = ph0;
      ol[(size_t)wid*16 + lane]     = pl0;
      oh[(size_t)wid*16 + 8 + lane] = ph1;
      ol[(size_t)wid*16 + 8 + lane] = pl1;
    }
  }
}

extern "C" void kernel_launch(void* const* d_in, const int* in_sizes, int n_in,
                              void* d_out, int out_size, void* d_ws, size_t ws_size,
                              hipStream_t stream)
{
  const float* x   = (const float*)d_in[0];
  const int*   ei  = (const int*)d_in[1];
  const float* W1  = (const float*)d_in[2];
  const float* aS1 = (const float*)d_in[3];
  const float* aD1 = (const float*)d_in[4];
  const float* b1  = (const float*)d_in[5];
  const float* W2  = (const float*)d_in[6];
  const float* aS2 = (const float*)d_in[7];
  const float* aD2 = (const float*)d_in[8];
  const float* b2  = (const float*)d_in[9];
  const float* Wfc = (const float*)d_in[10];
  const float* bfc = (const float*)d_in[11];
  float* out = (float*)d_out;

  int n = in_sizes[0] / FD;
  int E = in_sizes[1] / 2;
  int etot = E + n;
  unsigned rscale = (unsigned)(((8ULL << 32) + n - 1) / (unsigned long long)n);

  char* p = (char*)d_ws;
  auto alloc = [&](size_t bytes)->void*{
    void* r = (void*)p;
    p += (bytes + 255) & ~(size_t)255;
    return r;
  };
  int* counts    = (int*)alloc((size_t)n * 4);
  int* offsets   = (int*)alloc((size_t)(n + 1) * 4);
  int* csr       = (int*)alloc((size_t)etot * 4);
  float* attS1   = (float*)alloc((size_t)n * 4 * 4);
  float* attD1   = (float*)alloc((size_t)n * 4 * 4);
  float* attS2   = (float*)alloc((size_t)n * 4 * 4);
  float* attD2   = (float*)alloc((size_t)n * 4 * 4);
  unsigned short* WT1h = (unsigned short*)alloc(144*FD*2);
  unsigned short* WT1l = (unsigned short*)alloc(144*FD*2);
  unsigned short* WT2h = (unsigned short*)alloc(144*FD*2);
  unsigned short* WT2l = (unsigned short*)alloc(144*FD*2);
  uint4* H16     = (uint4*)alloc((size_t)n * FD * 2);
  uint4* H2h     = (uint4*)alloc((size_t)n * FD * 2);
  uint4* H2l     = (uint4*)alloc((size_t)n * FD * 2);

  hipMemsetAsync(counts, 0, (size_t)n * 4, stream);

  const int NB_PART = 512;            // 64 chunks x 8 XCD-filtered block groups
  count_wprep_kernel<<<NB_PART + 144, 256, 0, stream>>>(ei + E, counts, E, rscale,
      NB_PART/8, NB_PART, W1, W2, aS1, aD1, aS2, aD2, WT1h, WT1l, WT2h, WT2l);
  scan_kernel<<<1, 1024, 0, stream>>>(counts, offsets, csr, n);
  fill_part_kernel<<<NB_PART, 256, 0, stream>>>(ei, offsets, counts, csr, E, rscale, NB_PART/8);

  int gb = (n + 63) / 64;
  int ab = (int)(((size_t)n * 64 + 255) / 256);

  // layer 1
  gemm_mfma_kernel<0><<<gb, 256, 0, stream>>>(x, nullptr, nullptr, WT1h, WT1l,
                                              H16, attS1, attD1, n);
  agg_kernel<0><<<ab, 256, 0, stream>>>(H16, attS1, attD1, csr, offsets,
                                        b1, nullptr, nullptr, H2h, H2l, nullptr, n);
  // layer 2 (+ fused FC)
  gemm_mfma_kernel<1><<<gb, 256, 0, stream>>>(nullptr, (const unsigned short*)H2h,
                                              (const unsigned short*)H2l, WT2h, WT2l,
                                              H16, attS2, attD2, n);
  agg_kernel<1><<<ab, 256, 0, stream>>>(H16, attS2, attD2, csr, offsets,
                                        b2, Wfc, bfc, nullptr, nullptr, out, n);
}

// Round 7
// 241.006 us; speedup vs baseline: 1.3117x; 1.3117x over previous
//
#include <hip/hip_runtime.h>
#include <hip/hip_fp16.h>

#define FD 128

typedef __attribute__((ext_vector_type(8))) short bf16x8;
typedef __attribute__((ext_vector_type(4))) float f32x4;

__device__ __forceinline__ float lrelu(float x, float s){ return x > 0.f ? x : s*x; }

__device__ __forceinline__ unsigned short f2bf(float f){
  unsigned u = __builtin_bit_cast(unsigned, f);
  return (unsigned short)((u + 0x7FFFu + ((u >> 16) & 1u)) >> 16);
}
__device__ __forceinline__ float bf2f(unsigned short h){
  unsigned u = ((unsigned)h) << 16;
  return __builtin_bit_cast(float, u);
}

// WT storage (per layer): single ushort buffer, 36864 entries = 73728 B.
//   [0, 18432)     : hi part, XOR-swizzled row-major [144][128]
//   [18432, 36864) : lo part, same layout
// swizzled index for (row w, k): si = w*128 + (k ^ ((w&7)<<3))
// (XOR on ushort-index bits 3..5 == byte-bits 4..6 -> bank-conflict-free ds_read_b128)

// ---------------- count (XCD-partitioned) + wprep fused ----------------
__global__ __launch_bounds__(256) void count_wprep_kernel(const int* __restrict__ dst,
    int* __restrict__ counts, int E, unsigned rscale, int nchunk, int nbc,
    const float* __restrict__ W1, const float* __restrict__ W2,
    const float* __restrict__ aS1, const float* __restrict__ aD1,
    const float* __restrict__ aS2, const float* __restrict__ aD2,
    unsigned short* __restrict__ WT1, unsigned short* __restrict__ WT2)
{
  int b = blockIdx.x;
  if (b < nbc){
    int xcd = b & 7, chunk = b >> 3;
    int nv = E >> 2;
    for (int v = chunk*256 + threadIdx.x; v < nv; v += nchunk*256){
      int4 d4 = ((const int4*)dst)[v];
      #pragma unroll
      for (int t = 0; t < 4; ++t){
        int d = (&d4.x)[t];
        unsigned r = (unsigned)(((unsigned long long)(unsigned)d * rscale) >> 32);
        if ((int)r == xcd) atomicAdd(&counts[d], 1);
      }
    }
    if (chunk == 0 && threadIdx.x < (E & 3)){
      int i = (E & ~3) + threadIdx.x;
      int d = dst[i];
      unsigned r = (unsigned)(((unsigned long long)(unsigned)d * rscale) >> 32);
      if ((int)r == xcd) atomicAdd(&counts[d], 1);
    }
    return;
  }
  int id = (b - nbc)*256 + threadIdx.x;
  if (id < 32768){
    const float* W = (id < 16384) ? W1 : W2;
    unsigned short* T = (id < 16384) ? WT1 : WT2;
    int idx = id & 16383;
    int k = idx >> 7, c = idx & 127;
    int w = ((c & 7) << 4) | (c >> 3);   // channel c -> row w (thread (ct,r) -> ch r*8+ct)
    int si = w*128 + (k ^ ((w & 7) << 3));
    float v = W[idx];
    unsigned short h = f2bf(v);
    T[si] = h;
    T[18432 + si] = f2bf(v - bf2f(h));
  } else if (id < 34816){
    int id2 = id - 32768;
    int layer = id2 >> 10;
    int id3 = id2 & 1023;
    int k = id3 >> 3, cc = id3 & 7;
    const float* W  = layer ? W2 : W1;
    const float* av = (cc < 4) ? (layer ? aS2 : aS1) : (layer ? aD2 : aD1);
    unsigned short* T = layer ? WT2 : WT1;
    int h = cc & 3, base = h*32;
    float acc = 0.f;
    #pragma unroll 8
    for (int c = 0; c < 32; ++c) acc += W[k*FD + base + c] * av[base + c];
    int w = 128 + cc;
    int si = w*128 + (k ^ ((w & 7) << 3));
    unsigned short hh = f2bf(acc);
    T[si] = hh;
    T[18432 + si] = f2bf(acc - bf2f(hh));
  } else if (id < 36864){
    int id2 = id - 34816;
    int layer = id2 >> 10;
    int id3 = id2 & 1023;
    int w = 136 + (id3 >> 7), k = id3 & 127;
    unsigned short* T = layer ? WT2 : WT1;
    int si = w*128 + (k ^ ((w & 7) << 3));
    T[si] = 0;
    T[18432 + si] = 0;
  }
}

// ---------------- scan of (counts[i]+1) + self-loop insertion ----------------
__global__ __launch_bounds__(1024) void scan_kernel(const int* __restrict__ counts,
                                                    int* __restrict__ offsets,
                                                    int* __restrict__ csr, int n){
  __shared__ int wsum[16];
  __shared__ int carry_s;
  int tid = threadIdx.x, lane = tid & 63, wv = tid >> 6;
  if (tid == 0) carry_s = 0;
  __syncthreads();
  for (int base = 0; base < n; base += 4096){
    int idx = base + tid*4;
    int v0=0,v1=0,v2=0,v3=0;
    if (idx + 3 < n){
      int4 t = *(const int4*)(counts + idx);
      v0=t.x+1; v1=t.y+1; v2=t.z+1; v3=t.w+1;
    } else {
      if (idx   < n) v0 = counts[idx]+1;
      if (idx+1 < n) v1 = counts[idx+1]+1;
      if (idx+2 < n) v2 = counts[idx+2]+1;
      if (idx+3 < n) v3 = counts[idx+3]+1;
    }
    int p0=v0, p1=p0+v1, p2=p1+v2, p3=p2+v3;
    int incl = p3;
    #pragma unroll
    for (int off = 1; off < 64; off <<= 1){
      int t = __shfl_up(incl, off);
      if (lane >= off) incl += t;
    }
    if (lane == 63) wsum[wv] = incl;
    __syncthreads();
    if (wv == 0 && lane < 16){
      int s = wsum[lane];
      #pragma unroll
      for (int off = 1; off < 16; off <<= 1){
        int t = __shfl_up(s, off);
        if (lane >= off) s += t;
      }
      wsum[lane] = s;
    }
    __syncthreads();
    int woff = (wv > 0) ? wsum[wv-1] : 0;
    int carry = carry_s;
    int off0 = carry + woff + incl - p3;
    if (idx   < n){ offsets[idx]   = off0;      csr[off0 + p0 - 1] = idx;   }
    if (idx+1 < n){ offsets[idx+1] = off0 + p0; csr[off0 + p1 - 1] = idx+1; }
    if (idx+2 < n){ offsets[idx+2] = off0 + p1; csr[off0 + p2 - 1] = idx+2; }
    if (idx+3 < n){ offsets[idx+3] = off0 + p2; csr[off0 + p3 - 1] = idx+3; }
    __syncthreads();
    if (tid == 0) carry_s = carry + wsum[15];
    __syncthreads();
  }
  if (tid == 0) offsets[n] = carry_s;
}

// ---------------- fill (XCD-partitioned; slots 0..deg-1) ----------------
__global__ __launch_bounds__(256) void fill_part_kernel(const int* __restrict__ ei,
    const int* __restrict__ offsets, int* __restrict__ counts, int* __restrict__ csr,
    int E, unsigned rscale, int nchunk){
  int b = blockIdx.x;
  int xcd = b & 7, chunk = b >> 3;
  int nv = E >> 2;
  for (int v = chunk*256 + threadIdx.x; v < nv; v += nchunk*256){
    int4 s4 = ((const int4*)ei)[v];
    int4 d4 = ((const int4*)(ei + E))[v];
    #pragma unroll
    for (int t = 0; t < 4; ++t){
      int d = (&d4.x)[t];
      unsigned r = (unsigned)(((unsigned long long)(unsigned)d * rscale) >> 32);
      if ((int)r == xcd){
        int c = atomicSub(&counts[d], 1) - 1;
        csr[offsets[d] + c] = (&s4.x)[t];
      }
    }
  }
  if (chunk == 0 && threadIdx.x < (E & 3)){
    int i = (E & ~3) + threadIdx.x;
    int d = ei[E + i];
    unsigned r = (unsigned)(((unsigned long long)(unsigned)d * rscale) >> 32);
    if ((int)r == xcd){
      int c = atomicSub(&counts[d], 1) - 1;
      csr[offsets[d] + c] = ei[i];
    }
  }
}

// ---------------- MFMA GEMM: [H(fp16, packed) | attS | attD] ----------------
// B operand (WT) staged in LDS once per block (73.7 KB), shared by 4 waves ->
// 8x less L2 traffic than per-wave streaming. ds_read_b128 on the XOR-swizzled
// layout is bank-conflict-free.
template<int SPLITIN>
__global__ __launch_bounds__(256) void gemm_mfma_kernel(
    const float* __restrict__ Xf,
    const unsigned short* __restrict__ Xh, const unsigned short* __restrict__ Xl,
    const unsigned short* __restrict__ WT,
    uint4* __restrict__ H16, float* __restrict__ attS, float* __restrict__ attD, int n)
{
  __shared__ unsigned short smem[36864];     // 73728 B: [hi 18432][lo 18432]
  int tid = threadIdx.x;
  int wv = tid >> 6, lane = tid & 63;
  int g = lane >> 4, r = lane & 15;
  int rbase = blockIdx.x*64 + wv*16;
  int arow = rbase + r; if (arow >= n) arow = n - 1;

  // stage WT -> LDS (linear copy; WT already stored swizzled)
  {
    const uint4* src = (const uint4*)WT;
    uint4* dst = (uint4*)smem;
    #pragma unroll
    for (int i = 0; i < 18; ++i) dst[tid + i*256] = src[tid + i*256];
  }

  bf16x8 Ah[4], Al[4];
  if (SPLITIN){
    const bf16x8* ph = (const bf16x8*)(Xh + (size_t)arow*FD);
    const bf16x8* pl = (const bf16x8*)(Xl + (size_t)arow*FD);
    #pragma unroll
    for (int kc = 0; kc < 4; ++kc){ Ah[kc] = ph[kc*4 + g]; Al[kc] = pl[kc*4 + g]; }
  } else {
    const float4* px = (const float4*)(Xf + (size_t)arow*FD);
    #pragma unroll
    for (int kc = 0; kc < 4; ++kc){
      float4 x0 = px[(kc*4 + g)*2];
      float4 x1 = px[(kc*4 + g)*2 + 1];
      float xs[8] = {x0.x,x0.y,x0.z,x0.w,x1.x,x1.y,x1.z,x1.w};
      #pragma unroll
      for (int t = 0; t < 8; ++t){
        unsigned short hh = f2bf(xs[t]);
        Ah[kc][t] = (short)hh;
        Al[kc][t] = (short)f2bf(xs[t] - bf2f(hh));
      }
    }
  }

  __syncthreads();   // LDS staging complete

  f32x4 acc[9];
  #pragma unroll
  for (int ct = 0; ct < 9; ++ct) acc[ct] = (f32x4){0.f,0.f,0.f,0.f};

  #pragma unroll
  for (int ct = 0; ct < 9; ++ct){
    int wrow = ct*16 + r;
    int sw = (wrow & 7) << 3;
    #pragma unroll
    for (int kc = 0; kc < 4; ++kc){
      int kidx = (kc*32 + g*8) ^ sw;
      bf16x8 Bh = *(const bf16x8*)&smem[wrow*128 + kidx];
      bf16x8 Bl = *(const bf16x8*)&smem[18432 + wrow*128 + kidx];
      acc[ct] = __builtin_amdgcn_mfma_f32_16x16x32_bf16(Ah[kc], Bh, acc[ct], 0, 0, 0);
      acc[ct] = __builtin_amdgcn_mfma_f32_16x16x32_bf16(Ah[kc], Bl, acc[ct], 0, 0, 0);
      acc[ct] = __builtin_amdgcn_mfma_f32_16x16x32_bf16(Al[kc], Bh, acc[ct], 0, 0, 0);
    }
  }

  #pragma unroll
  for (int j = 0; j < 4; ++j){
    int row = rbase + g*4 + j;
    if (row < n){
      __half2 p0 = __float22half2_rn(make_float2(acc[0][j], acc[1][j]));
      __half2 p1 = __float22half2_rn(make_float2(acc[2][j], acc[3][j]));
      __half2 p2 = __float22half2_rn(make_float2(acc[4][j], acc[5][j]));
      __half2 p3 = __float22half2_rn(make_float2(acc[6][j], acc[7][j]));
      uint4 pk;
      pk.x = __builtin_bit_cast(unsigned, p0);
      pk.y = __builtin_bit_cast(unsigned, p1);
      pk.z = __builtin_bit_cast(unsigned, p2);
      pk.w = __builtin_bit_cast(unsigned, p3);
      H16[(size_t)row*16 + r] = pk;
      if (r < 4)      attS[row*4 + r]       = acc[8][j];
      else if (r < 8) attD[row*4 + (r - 4)] = acc[8][j];
    }
  }
}

// ---------------- per-dst softmax + aggregate (one wave per dst) ----------------
// Round-5 structure (proven): 4 edges/iter, 16 lanes/edge, stride-5 stash
// (gcd(5,32)=1 -> conflict-free). No max-subtraction (logits bounded).
// acc[0..3] = ch 4r..4r+3 (head r<8?0:1); acc[4..7] = 64+4r..+3 (head r<8?2:3).
template<int OUT>
__global__ __launch_bounds__(256) void agg_kernel(
    const uint2* __restrict__ H16, const float* __restrict__ attS, const float* __restrict__ attD,
    const int* __restrict__ csr, const int* __restrict__ offsets,
    const float* __restrict__ bias, const float* __restrict__ wfc, const float* __restrict__ bfc,
    unsigned short* __restrict__ oh, unsigned short* __restrict__ ol,
    float* __restrict__ out, int n)
{
  __shared__ float lds[4][64*5];
  int wid = (int)((blockIdx.x * (size_t)blockDim.x + threadIdx.x) >> 6);
  int lane = threadIdx.x & 63;
  if (wid >= n) return;
  int g = lane >> 4, r = lane & 15;
  int selA = (r >> 3) & 1;
  float* wl = lds[threadIdx.x >> 6];
  int* wli = (int*)wl;

  int start = offsets[wid], end = offsets[wid+1];
  float4 ad4 = ((const float4*)attD)[wid];

  float z0=0.f, z1=0.f, z2=0.f, z3=0.f;
  float acc[8];
  #pragma unroll
  for (int k = 0; k < 8; ++k) acc[k] = 0.f;

  for (int base2 = start; base2 < end; base2 += 64){
    int cnt = end - base2; if (cnt > 64) cnt = 64;
    float p0,p1,p2,p3; int sb = 0;
    if (lane < cnt){
      int s = csr[base2 + lane];
      sb = s << 5;                    // 32 uint2 per 256B fp16 row
      float4 as4 = ((const float4*)attS)[s];
      p0 = __expf(lrelu(as4.x + ad4.x, 0.2f));
      p1 = __expf(lrelu(as4.y + ad4.y, 0.2f));
      p2 = __expf(lrelu(as4.z + ad4.z, 0.2f));
      p3 = __expf(lrelu(as4.w + ad4.w, 0.2f));
    } else { p0=p1=p2=p3=0.f; }
    z0+=p0; z1+=p1; z2+=p2; z3+=p3;
    wli[lane*5]  = sb;
    wl[lane*5+1] = p0; wl[lane*5+2] = p1; wl[lane*5+3] = p2; wl[lane*5+4] = p3;
    asm volatile("s_waitcnt lgkmcnt(0)" ::: "memory");
    __builtin_amdgcn_sched_barrier(0);
    for (int jj = g; jj < cnt; jj += 4){
      int sbj  = wli[jj*5];
      float pA = wl[jj*5 + 1 + selA];
      float pB = wl[jj*5 + 3 + selA];
      uint2 u0 = H16[(unsigned)(sbj + r)];
      uint2 u1 = H16[(unsigned)(sbj + 16 + r)];
      float2 a0 = __half22float2(__builtin_bit_cast(__half2, u0.x));
      float2 a1 = __half22float2(__builtin_bit_cast(__half2, u0.y));
      float2 a2 = __half22float2(__builtin_bit_cast(__half2, u1.x));
      float2 a3 = __half22float2(__builtin_bit_cast(__half2, u1.y));
      acc[0] += pA*a0.x; acc[1] += pA*a0.y; acc[2] += pA*a1.x; acc[3] += pA*a1.y;
      acc[4] += pB*a2.x; acc[5] += pB*a2.y; acc[6] += pB*a3.x; acc[7] += pB*a3.y;
    }
    __builtin_amdgcn_sched_barrier(0);
  }

  #pragma unroll
  for (int off = 32; off >= 1; off >>= 1){
    z0+=__shfl_xor(z0,off); z1+=__shfl_xor(z1,off);
    z2+=__shfl_xor(z2,off); z3+=__shfl_xor(z3,off);
  }
  #pragma unroll
  for (int k = 0; k < 8; ++k){
    acc[k] += __shfl_xor(acc[k], 16);
    acc[k] += __shfl_xor(acc[k], 32);
  }
  // group g keeps channels ch0 = (g>>1)*64 + 4r + 2*(g&1), ch1 = ch0+1
  float o0 = g==0?acc[0]:g==1?acc[2]:g==2?acc[4]:acc[6];
  float o1 = g==0?acc[1]:g==1?acc[3]:g==2?acc[5]:acc[7];
  int ch0 = ((g>>1)<<6) + (r<<2) + ((g&1)<<1);
  float zz = (g < 2) ? ((r<8)? z0 : z1) : ((r<8)? z2 : z3);
  float inv = 1.f / (zz + 1e-16f);
  float2 b2v = ((const float2*)bias)[ch0 >> 1];
  o0 = lrelu(o0*inv + b2v.x, 0.01f);
  o1 = lrelu(o1*inv + b2v.y, 0.01f);
  if (OUT){
    float2 w2v = ((const float2*)wfc)[ch0 >> 1];
    float t = o0*w2v.x + o1*w2v.y;
    #pragma unroll
    for (int off = 32; off >= 1; off >>= 1) t += __shfl_xor(t, off);
    if (lane == 0) out[wid] = t + bfc[0];
  } else {
    unsigned short h0 = f2bf(o0);
    unsigned short h1 = f2bf(o1);
    unsigned short l0 = f2bf(o0 - bf2f(h0));
    unsigned short l1 = f2bf(o1 - bf2f(h1));
    ((unsigned*)oh)[(size_t)wid*64 + (ch0>>1)] = (unsigned)h0 | ((unsigned)h1 << 16);
    ((unsigned*)ol)[(size_t)wid*64 + (ch0>>1)] = (unsigned)l0 | ((unsigned)l1 << 16);
  }
}

extern "C" void kernel_launch(void* const* d_in, const int* in_sizes, int n_in,
                              void* d_out, int out_size, void* d_ws, size_t ws_size,
                              hipStream_t stream)
{
  const float* x   = (const float*)d_in[0];
  const int*   ei  = (const int*)d_in[1];
  const float* W1  = (const float*)d_in[2];
  const float* aS1 = (const float*)d_in[3];
  const float* aD1 = (const float*)d_in[4];
  const float* b1  = (const float*)d_in[5];
  const float* W2  = (const float*)d_in[6];
  const float* aS2 = (const float*)d_in[7];
  const float* aD2 = (const float*)d_in[8];
  const float* b2  = (const float*)d_in[9];
  const float* Wfc = (const float*)d_in[10];
  const float* bfc = (const float*)d_in[11];
  float* out = (float*)d_out;

  int n = in_sizes[0] / FD;
  int E = in_sizes[1] / 2;
  int etot = E + n;
  unsigned rscale = (unsigned)(((8ULL << 32) + n - 1) / (unsigned long long)n);

  char* p = (char*)d_ws;
  auto alloc = [&](size_t bytes)->void*{
    void* r = (void*)p;
    p += (bytes + 255) & ~(size_t)255;
    return r;
  };
  int* counts    = (int*)alloc((size_t)n * 4);
  int* offsets   = (int*)alloc((size_t)(n + 1) * 4);
  int* csr       = (int*)alloc((size_t)etot * 4);
  float* attS1   = (float*)alloc((size_t)n * 4 * 4);
  float* attD1   = (float*)alloc((size_t)n * 4 * 4);
  float* attS2   = (float*)alloc((size_t)n * 4 * 4);
  float* attD2   = (float*)alloc((size_t)n * 4 * 4);
  unsigned short* WT1 = (unsigned short*)alloc(36864*2);
  unsigned short* WT2 = (unsigned short*)alloc(36864*2);
  uint4* H16     = (uint4*)alloc((size_t)n * FD * 2);
  unsigned short* H2h = (unsigned short*)alloc((size_t)n * FD * 2);
  unsigned short* H2l = (unsigned short*)alloc((size_t)n * FD * 2);

  hipMemsetAsync(counts, 0, (size_t)n * 4, stream);

  const int NB_PART = 512;            // 64 chunks x 8 XCD-filtered block groups
  count_wprep_kernel<<<NB_PART + 144, 256, 0, stream>>>(ei + E, counts, E, rscale,
      NB_PART/8, NB_PART, W1, W2, aS1, aD1, aS2, aD2, WT1, WT2);
  scan_kernel<<<1, 1024, 0, stream>>>(counts, offsets, csr, n);
  fill_part_kernel<<<NB_PART, 256, 0, stream>>>(ei, offsets, counts, csr, E, rscale, NB_PART/8);

  int gb = (n + 63) / 64;
  int ab = (int)(((size_t)n * 64 + 255) / 256);

  // layer 1
  gemm_mfma_kernel<0><<<gb, 256, 0, stream>>>(x, nullptr, nullptr, WT1,
                                              H16, attS1, attD1, n);
  agg_kernel<0><<<ab, 256, 0, stream>>>((const uint2*)H16, attS1, attD1, csr, offsets,
                                        b1, nullptr, nullptr, H2h, H2l, nullptr, n);
  // layer 2 (+ fused FC)
  gemm_mfma_kernel<1><<<gb, 256, 0, stream>>>(nullptr, H2h, H2l, WT2,
                                              H16, attS2, attD2, n);
  agg_kernel<1><<<ab, 256, 0, stream>>>((const uint2*)H16, attS2, attD2, csr, offsets,
                                        b2, Wfc, bfc, nullptr, nullptr, out, n);
}

// Round 8
// 204.174 us; speedup vs baseline: 1.5483x; 1.1804x over previous
//
#include <hip/hip_runtime.h>
#include <hip/hip_fp16.h>

#define FD 128

typedef __attribute__((ext_vector_type(8))) short bf16x8;
typedef __attribute__((ext_vector_type(4))) float f32x4;

__device__ __forceinline__ float lrelu(float x, float s){ return x > 0.f ? x : s*x; }

__device__ __forceinline__ unsigned short f2bf(float f){
  unsigned u = __builtin_bit_cast(unsigned, f);
  return (unsigned short)((u + 0x7FFFu + ((u >> 16) & 1u)) >> 16);
}
__device__ __forceinline__ float bf2f(unsigned short h){
  unsigned u = ((unsigned)h) << 16;
  return __builtin_bit_cast(float, u);
}

// WT storage (per layer): single ushort buffer, 36864 entries = 73728 B.
//   [0, 18432)     : hi part, XOR-swizzled row-major [144][128]
//   [18432, 36864) : lo part, same layout
// swizzled index for (row w, k): si = w*128 + (k ^ ((w&7)<<3))

// ---------------- count (XCD-partitioned) + wprep fused ----------------
__global__ __launch_bounds__(256) void count_wprep_kernel(const int* __restrict__ dst,
    int* __restrict__ counts, int E, unsigned rscale, int nchunk, int nbc,
    const float* __restrict__ W1, const float* __restrict__ W2,
    const float* __restrict__ aS1, const float* __restrict__ aD1,
    const float* __restrict__ aS2, const float* __restrict__ aD2,
    unsigned short* __restrict__ WT1, unsigned short* __restrict__ WT2)
{
  int b = blockIdx.x;
  if (b < nbc){
    int xcd = b & 7, chunk = b >> 3;
    int nv = E >> 2;
    for (int v = chunk*256 + threadIdx.x; v < nv; v += nchunk*256){
      int4 d4 = ((const int4*)dst)[v];
      #pragma unroll
      for (int t = 0; t < 4; ++t){
        int d = (&d4.x)[t];
        unsigned r = (unsigned)(((unsigned long long)(unsigned)d * rscale) >> 32);
        if ((int)r == xcd) atomicAdd(&counts[d], 1);
      }
    }
    if (chunk == 0 && threadIdx.x < (E & 3)){
      int i = (E & ~3) + threadIdx.x;
      int d = dst[i];
      unsigned r = (unsigned)(((unsigned long long)(unsigned)d * rscale) >> 32);
      if ((int)r == xcd) atomicAdd(&counts[d], 1);
    }
    return;
  }
  int id = (b - nbc)*256 + threadIdx.x;
  if (id < 32768){
    const float* W = (id < 16384) ? W1 : W2;
    unsigned short* T = (id < 16384) ? WT1 : WT2;
    int idx = id & 16383;
    int k = idx >> 7, c = idx & 127;
    int w = ((c & 7) << 4) | (c >> 3);   // channel c -> row w (thread (ct,r) -> ch r*8+ct)
    int si = w*128 + (k ^ ((w & 7) << 3));
    float v = W[idx];
    unsigned short h = f2bf(v);
    T[si] = h;
    T[18432 + si] = f2bf(v - bf2f(h));
  } else if (id < 34816){
    int id2 = id - 32768;
    int layer = id2 >> 10;
    int id3 = id2 & 1023;
    int k = id3 >> 3, cc = id3 & 7;
    const float* W  = layer ? W2 : W1;
    const float* av = (cc < 4) ? (layer ? aS2 : aS1) : (layer ? aD2 : aD1);
    unsigned short* T = layer ? WT2 : WT1;
    int h = cc & 3, base = h*32;
    float acc = 0.f;
    #pragma unroll 8
    for (int c = 0; c < 32; ++c) acc += W[k*FD + base + c] * av[base + c];
    int w = 128 + cc;
    int si = w*128 + (k ^ ((w & 7) << 3));
    unsigned short hh = f2bf(acc);
    T[si] = hh;
    T[18432 + si] = f2bf(acc - bf2f(hh));
  } else if (id < 36864){
    int id2 = id - 34816;
    int layer = id2 >> 10;
    int id3 = id2 & 1023;
    int w = 136 + (id3 >> 7), k = id3 & 127;
    unsigned short* T = layer ? WT2 : WT1;
    int si = w*128 + (k ^ ((w & 7) << 3));
    T[si] = 0;
    T[18432 + si] = 0;
  }
}

// ---------------- multi-block scan of (counts[i]+1), 3 phases ----------------
// scan1: per-block inclusive scan -> offsets[i] (local), blocksum[b].
__global__ __launch_bounds__(512) void scan1_kernel(const int* __restrict__ counts,
    int* __restrict__ offsets, int* __restrict__ blocksum, int n){
  __shared__ int wsum[8];
  int tid = threadIdx.x, lane = tid & 63, wv = tid >> 6;
  int i = blockIdx.x*512 + tid;
  int v = (i < n) ? counts[i] + 1 : 0;
  int incl = v;
  #pragma unroll
  for (int off = 1; off < 64; off <<= 1){
    int t = __shfl_up(incl, off);
    if (lane >= off) incl += t;
  }
  if (lane == 63) wsum[wv] = incl;
  __syncthreads();
  if (wv == 0 && lane < 8){
    int s = wsum[lane];
    #pragma unroll
    for (int off = 1; off < 8; off <<= 1){
      int t = __shfl_up(s, off);
      if (lane >= off) s += t;
    }
    wsum[lane] = s;
  }
  __syncthreads();
  int woff = (wv > 0) ? wsum[wv-1] : 0;
  incl += woff;
  if (i < n) offsets[i] = incl;          // local inclusive
  if (tid == 511) blocksum[blockIdx.x] = incl;
}

// scan2: one wave; nb <= 128 block sums -> exclusive block offsets (in place);
// writes offsets[n] = grand total.
__global__ __launch_bounds__(64) void scan2_kernel(int* __restrict__ blocksum,
    int* __restrict__ offsets, int nb, int n){
  int lane = threadIdx.x;
  int i0 = 2*lane, i1 = 2*lane + 1;
  int v0 = (i0 < nb) ? blocksum[i0] : 0;
  int v1 = (i1 < nb) ? blocksum[i1] : 0;
  int pair = v0 + v1;
  int incl = pair;
  #pragma unroll
  for (int off = 1; off < 64; off <<= 1){
    int t = __shfl_up(incl, off);
    if (lane >= off) incl += t;
  }
  int excl = incl - pair;
  if (i0 < nb) blocksum[i0] = excl;
  if (i1 < nb) blocksum[i1] = excl + v0;
  if (lane == 63) offsets[n] = incl;
}

// scan3: finalize offsets (exclusive, global) + write self-loop csr entries.
__global__ __launch_bounds__(512) void scan3_kernel(const int* __restrict__ counts,
    int* __restrict__ offsets, const int* __restrict__ blocksum,
    int* __restrict__ csr, int n){
  int i = blockIdx.x*512 + threadIdx.x;
  if (i >= n) return;
  int v = counts[i] + 1;
  int gl = offsets[i] + blocksum[blockIdx.x];
  offsets[i] = gl - v;
  csr[gl - 1] = i;
}

// ---------------- fill (XCD-partitioned; slots 0..deg-1) ----------------
__global__ __launch_bounds__(256) void fill_part_kernel(const int* __restrict__ ei,
    const int* __restrict__ offsets, int* __restrict__ counts, int* __restrict__ csr,
    int E, unsigned rscale, int nchunk){
  int b = blockIdx.x;
  int xcd = b & 7, chunk = b >> 3;
  int nv = E >> 2;
  for (int v = chunk*256 + threadIdx.x; v < nv; v += nchunk*256){
    int4 s4 = ((const int4*)ei)[v];
    int4 d4 = ((const int4*)(ei + E))[v];
    #pragma unroll
    for (int t = 0; t < 4; ++t){
      int d = (&d4.x)[t];
      unsigned r = (unsigned)(((unsigned long long)(unsigned)d * rscale) >> 32);
      if ((int)r == xcd){
        int c = atomicSub(&counts[d], 1) - 1;
        csr[offsets[d] + c] = (&s4.x)[t];
      }
    }
  }
  if (chunk == 0 && threadIdx.x < (E & 3)){
    int i = (E & ~3) + threadIdx.x;
    int d = ei[E + i];
    unsigned r = (unsigned)(((unsigned long long)(unsigned)d * rscale) >> 32);
    if ((int)r == xcd){
      int c = atomicSub(&counts[d], 1) - 1;
      csr[offsets[d] + c] = ei[i];
    }
  }
}

// ---------------- MFMA GEMM: [H(fp16, packed) | attS | attD] ----------------
// B operand (WT) staged in LDS once per block (73.7 KB), shared by 4 waves.
// ds_read_b128 on the XOR-swizzled layout is bank-conflict-free.
template<int SPLITIN>
__global__ __launch_bounds__(256) void gemm_mfma_kernel(
    const float* __restrict__ Xf,
    const unsigned short* __restrict__ Xh, const unsigned short* __restrict__ Xl,
    const unsigned short* __restrict__ WT,
    uint4* __restrict__ H16, float* __restrict__ attS, float* __restrict__ attD, int n)
{
  __shared__ unsigned short smem[36864];     // 73728 B: [hi 18432][lo 18432]
  int tid = threadIdx.x;
  int wv = tid >> 6, lane = tid & 63;
  int g = lane >> 4, r = lane & 15;
  int rbase = blockIdx.x*64 + wv*16;
  int arow = rbase + r; if (arow >= n) arow = n - 1;

  {
    const uint4* src = (const uint4*)WT;
    uint4* dst = (uint4*)smem;
    #pragma unroll
    for (int i = 0; i < 18; ++i) dst[tid + i*256] = src[tid + i*256];
  }

  bf16x8 Ah[4], Al[4];
  if (SPLITIN){
    const bf16x8* ph = (const bf16x8*)(Xh + (size_t)arow*FD);
    const bf16x8* pl = (const bf16x8*)(Xl + (size_t)arow*FD);
    #pragma unroll
    for (int kc = 0; kc < 4; ++kc){ Ah[kc] = ph[kc*4 + g]; Al[kc] = pl[kc*4 + g]; }
  } else {
    const float4* px = (const float4*)(Xf + (size_t)arow*FD);
    #pragma unroll
    for (int kc = 0; kc < 4; ++kc){
      float4 x0 = px[(kc*4 + g)*2];
      float4 x1 = px[(kc*4 + g)*2 + 1];
      float xs[8] = {x0.x,x0.y,x0.z,x0.w,x1.x,x1.y,x1.z,x1.w};
      #pragma unroll
      for (int t = 0; t < 8; ++t){
        unsigned short hh = f2bf(xs[t]);
        Ah[kc][t] = (short)hh;
        Al[kc][t] = (short)f2bf(xs[t] - bf2f(hh));
      }
    }
  }

  __syncthreads();

  f32x4 acc[9];
  #pragma unroll
  for (int ct = 0; ct < 9; ++ct) acc[ct] = (f32x4){0.f,0.f,0.f,0.f};

  #pragma unroll
  for (int ct = 0; ct < 9; ++ct){
    int wrow = ct*16 + r;
    int sw = (wrow & 7) << 3;
    #pragma unroll
    for (int kc = 0; kc < 4; ++kc){
      int kidx = (kc*32 + g*8) ^ sw;
      bf16x8 Bh = *(const bf16x8*)&smem[wrow*128 + kidx];
      bf16x8 Bl = *(const bf16x8*)&smem[18432 + wrow*128 + kidx];
      acc[ct] = __builtin_amdgcn_mfma_f32_16x16x32_bf16(Ah[kc], Bh, acc[ct], 0, 0, 0);
      acc[ct] = __builtin_amdgcn_mfma_f32_16x16x32_bf16(Ah[kc], Bl, acc[ct], 0, 0, 0);
      acc[ct] = __builtin_amdgcn_mfma_f32_16x16x32_bf16(Al[kc], Bh, acc[ct], 0, 0, 0);
    }
  }

  #pragma unroll
  for (int j = 0; j < 4; ++j){
    int row = rbase + g*4 + j;
    if (row < n){
      __half2 p0 = __float22half2_rn(make_float2(acc[0][j], acc[1][j]));
      __half2 p1 = __float22half2_rn(make_float2(acc[2][j], acc[3][j]));
      __half2 p2 = __float22half2_rn(make_float2(acc[4][j], acc[5][j]));
      __half2 p3 = __float22half2_rn(make_float2(acc[6][j], acc[7][j]));
      uint4 pk;
      pk.x = __builtin_bit_cast(unsigned, p0);
      pk.y = __builtin_bit_cast(unsigned, p1);
      pk.z = __builtin_bit_cast(unsigned, p2);
      pk.w = __builtin_bit_cast(unsigned, p3);
      H16[(size_t)row*16 + r] = pk;
      if (r < 4)      attS[row*4 + r]       = acc[8][j];
      else if (r < 8) attD[row*4 + (r - 4)] = acc[8][j];
    }
  }
}

// ---------------- per-dst softmax + aggregate (one wave per dst) ----------------
// Round-5 structure (proven): 4 edges/iter, 16 lanes/edge, stride-5 stash
// (gcd(5,32)=1 -> conflict-free). No max-subtraction (logits bounded).
template<int OUT>
__global__ __launch_bounds__(256) void agg_kernel(
    const uint2* __restrict__ H16, const float* __restrict__ attS, const float* __restrict__ attD,
    const int* __restrict__ csr, const int* __restrict__ offsets,
    const float* __restrict__ bias, const float* __restrict__ wfc, const float* __restrict__ bfc,
    unsigned short* __restrict__ oh, unsigned short* __restrict__ ol,
    float* __restrict__ out, int n)
{
  __shared__ float lds[4][64*5];
  int wid = (int)((blockIdx.x * (size_t)blockDim.x + threadIdx.x) >> 6);
  int lane = threadIdx.x & 63;
  if (wid >= n) return;
  int g = lane >> 4, r = lane & 15;
  int selA = (r >> 3) & 1;
  float* wl = lds[threadIdx.x >> 6];
  int* wli = (int*)wl;

  int start = offsets[wid], end = offsets[wid+1];
  float4 ad4 = ((const float4*)attD)[wid];

  float z0=0.f, z1=0.f, z2=0.f, z3=0.f;
  float acc[8];
  #pragma unroll
  for (int k = 0; k < 8; ++k) acc[k] = 0.f;

  for (int base2 = start; base2 < end; base2 += 64){
    int cnt = end - base2; if (cnt > 64) cnt = 64;
    float p0,p1,p2,p3; int sb = 0;
    if (lane < cnt){
      int s = csr[base2 + lane];
      sb = s << 5;                    // 32 uint2 per 256B fp16 row
      float4 as4 = ((const float4*)attS)[s];
      p0 = __expf(lrelu(as4.x + ad4.x, 0.2f));
      p1 = __expf(lrelu(as4.y + ad4.y, 0.2f));
      p2 = __expf(lrelu(as4.z + ad4.z, 0.2f));
      p3 = __expf(lrelu(as4.w + ad4.w, 0.2f));
    } else { p0=p1=p2=p3=0.f; }
    z0+=p0; z1+=p1; z2+=p2; z3+=p3;
    wli[lane*5]  = sb;
    wl[lane*5+1] = p0; wl[lane*5+2] = p1; wl[lane*5+3] = p2; wl[lane*5+4] = p3;
    asm volatile("s_waitcnt lgkmcnt(0)" ::: "memory");
    __builtin_amdgcn_sched_barrier(0);
    for (int jj = g; jj < cnt; jj += 4){
      int sbj  = wli[jj*5];
      float pA = wl[jj*5 + 1 + selA];
      float pB = wl[jj*5 + 3 + selA];
      uint2 u0 = H16[(unsigned)(sbj + r)];
      uint2 u1 = H16[(unsigned)(sbj + 16 + r)];
      float2 a0 = __half22float2(__builtin_bit_cast(__half2, u0.x));
      float2 a1 = __half22float2(__builtin_bit_cast(__half2, u0.y));
      float2 a2 = __half22float2(__builtin_bit_cast(__half2, u1.x));
      float2 a3 = __half22float2(__builtin_bit_cast(__half2, u1.y));
      acc[0] += pA*a0.x; acc[1] += pA*a0.y; acc[2] += pA*a1.x; acc[3] += pA*a1.y;
      acc[4] += pB*a2.x; acc[5] += pB*a2.y; acc[6] += pB*a3.x; acc[7] += pB*a3.y;
    }
    __builtin_amdgcn_sched_barrier(0);
  }

  #pragma unroll
  for (int off = 32; off >= 1; off >>= 1){
    z0+=__shfl_xor(z0,off); z1+=__shfl_xor(z1,off);
    z2+=__shfl_xor(z2,off); z3+=__shfl_xor(z3,off);
  }
  #pragma unroll
  for (int k = 0; k < 8; ++k){
    acc[k] += __shfl_xor(acc[k], 16);
    acc[k] += __shfl_xor(acc[k], 32);
  }
  float o0 = g==0?acc[0]:g==1?acc[2]:g==2?acc[4]:acc[6];
  float o1 = g==0?acc[1]:g==1?acc[3]:g==2?acc[5]:acc[7];
  int ch0 = ((g>>1)<<6) + (r<<2) + ((g&1)<<1);
  float zz = (g < 2) ? ((r<8)? z0 : z1) : ((r<8)? z2 : z3);
  float inv = 1.f / (zz + 1e-16f);
  float2 b2v = ((const float2*)bias)[ch0 >> 1];
  o0 = lrelu(o0*inv + b2v.x, 0.01f);
  o1 = lrelu(o1*inv + b2v.y, 0.01f);
  if (OUT){
    float2 w2v = ((const float2*)wfc)[ch0 >> 1];
    float t = o0*w2v.x + o1*w2v.y;
    #pragma unroll
    for (int off = 32; off >= 1; off >>= 1) t += __shfl_xor(t, off);
    if (lane == 0) out[wid] = t + bfc[0];
  } else {
    unsigned short h0 = f2bf(o0);
    unsigned short h1 = f2bf(o1);
    unsigned short l0 = f2bf(o0 - bf2f(h0));
    unsigned short l1 = f2bf(o1 - bf2f(h1));
    ((unsigned*)oh)[(size_t)wid*64 + (ch0>>1)] = (unsigned)h0 | ((unsigned)h1 << 16);
    ((unsigned*)ol)[(size_t)wid*64 + (ch0>>1)] = (unsigned)l0 | ((unsigned)l1 << 16);
  }
}

extern "C" void kernel_launch(void* const* d_in, const int* in_sizes, int n_in,
                              void* d_out, int out_size, void* d_ws, size_t ws_size,
                              hipStream_t stream)
{
  const float* x   = (const float*)d_in[0];
  const int*   ei  = (const int*)d_in[1];
  const float* W1  = (const float*)d_in[2];
  const float* aS1 = (const float*)d_in[3];
  const float* aD1 = (const float*)d_in[4];
  const float* b1  = (const float*)d_in[5];
  const float* W2  = (const float*)d_in[6];
  const float* aS2 = (const float*)d_in[7];
  const float* aD2 = (const float*)d_in[8];
  const float* b2  = (const float*)d_in[9];
  const float* Wfc = (const float*)d_in[10];
  const float* bfc = (const float*)d_in[11];
  float* out = (float*)d_out;

  int n = in_sizes[0] / FD;
  int E = in_sizes[1] / 2;
  int etot = E + n;
  unsigned rscale = (unsigned)(((8ULL << 32) + n - 1) / (unsigned long long)n);

  char* p = (char*)d_ws;
  auto alloc = [&](size_t bytes)->void*{
    void* r = (void*)p;
    p += (bytes + 255) & ~(size_t)255;
    return r;
  };
  int* counts    = (int*)alloc((size_t)n * 4);
  int* offsets   = (int*)alloc((size_t)(n + 1) * 4);
  int* blocksum  = (int*)alloc(1024 * 4);
  int* csr       = (int*)alloc((size_t)etot * 4);
  float* attS1   = (float*)alloc((size_t)n * 4 * 4);
  float* attD1   = (float*)alloc((size_t)n * 4 * 4);
  float* attS2   = (float*)alloc((size_t)n * 4 * 4);
  float* attD2   = (float*)alloc((size_t)n * 4 * 4);
  unsigned short* WT1 = (unsigned short*)alloc(36864*2);
  unsigned short* WT2 = (unsigned short*)alloc(36864*2);
  uint4* H16     = (uint4*)alloc((size_t)n * FD * 2);
  unsigned short* H2h = (unsigned short*)alloc((size_t)n * FD * 2);
  unsigned short* H2l = (unsigned short*)alloc((size_t)n * FD * 2);

  hipMemsetAsync(counts, 0, (size_t)n * 4, stream);

  const int NB_PART = 512;            // 64 chunks x 8 XCD-filtered block groups
  int nsb = (n + 511) / 512;          // scan blocks (<=128 for n<=65536)
  count_wprep_kernel<<<NB_PART + 144, 256, 0, stream>>>(ei + E, counts, E, rscale,
      NB_PART/8, NB_PART, W1, W2, aS1, aD1, aS2, aD2, WT1, WT2);
  scan1_kernel<<<nsb, 512, 0, stream>>>(counts, offsets, blocksum, n);
  scan2_kernel<<<1, 64, 0, stream>>>(blocksum, offsets, nsb, n);
  scan3_kernel<<<nsb, 512, 0, stream>>>(counts, offsets, blocksum, csr, n);
  fill_part_kernel<<<NB_PART, 256, 0, stream>>>(ei, offsets, counts, csr, E, rscale, NB_PART/8);

  int gb = (n + 63) / 64;
  int ab = (int)(((size_t)n * 64 + 255) / 256);

  // layer 1
  gemm_mfma_kernel<0><<<gb, 256, 0, stream>>>(x, nullptr, nullptr, WT1,
                                              H16, attS1, attD1, n);
  agg_kernel<0><<<ab, 256, 0, stream>>>((const uint2*)H16, attS1, attD1, csr, offsets,
                                        b1, nullptr, nullptr, H2h, H2l, nullptr, n);
  // layer 2 (+ fused FC)
  gemm_mfma_kernel<1><<<gb, 256, 0, stream>>>(nullptr, H2h, H2l, WT2,
                                              H16, attS2, attD2, n);
  agg_kernel<1><<<ab, 256, 0, stream>>>((const uint2*)H16, attS2, attD2, csr, offsets,
                                        b2, Wfc, bfc, nullptr, nullptr, out, n);
}